// Round 4
// baseline (9774.537 us; speedup 1.0000x reference)
//
#include <hip/hip_runtime.h>
#include <hip/hip_bf16.h>

// MLA forward. Storage dtype: fp32 (established round 2/3: runtime sniffer
// selected fp32 and passed; hard-coded bf16 NaN'd). Compute fp32.
// Outputs (flat fp32): out[8,388,608] | c_kv[2,097,152] | k_rot[2,097,152].
#define B_   2
#define S_   2048
#define E_   2048
#define H_   16
#define DH_  128
#define DR_  32
#define SP_  96
#define C_   512
#define M_   (B_ * S_)   // 4096 rows

// fp32 GEMM: out = A(MxK) @ W(KxN) + bias(N).
// fp32 dst index = m*orow + obase + (n/chunk)*gstride + n%chunk (head remap).
// Optional plain row-major copy to outB (d_out region, pre-offset by host).
__global__ __launch_bounds__(256) void gemm_kernel(
    const float* __restrict__ A, const float* __restrict__ W,
    const float* __restrict__ bias,
    float* __restrict__ outF, int orow, int chunk, int gstride, int obase,
    float* __restrict__ outB,
    int M, int N, int K) {
  __shared__ float As[16][64];   // [k][m]
  __shared__ float Bs[16][68];   // [k][n], padded
  int tid = threadIdx.x;
  int tx = tid & 15, ty = tid >> 4;
  int bm = blockIdx.y * 64, bn = blockIdx.x * 64;
  float acc[4][4] = {};

  int am  = tid >> 2;          // A tile row 0..63
  int ak  = (tid & 3) << 2;    // A tile k   0,4,8,12
  int bk  = tid >> 4;          // B tile k   0..15
  int bn0 = (tid & 15) << 2;   // B tile n   0..60

  const float* Aptr = A + (size_t)(bm + am) * K + ak;
  const float* Wptr = W + (size_t)bk * N + bn + bn0;

  for (int k0 = 0; k0 < K; k0 += 16) {
    float4 av = *(const float4*)(Aptr + k0);
    float4 wv = *(const float4*)(Wptr + (size_t)k0 * N);
    As[ak + 0][am] = av.x;
    As[ak + 1][am] = av.y;
    As[ak + 2][am] = av.z;
    As[ak + 3][am] = av.w;
    *(float4*)&Bs[bk][bn0] = wv;
    __syncthreads();
#pragma unroll
    for (int kk = 0; kk < 16; kk++) {
      float4 a = *(const float4*)&As[kk][ty << 2];
      float4 b = *(const float4*)&Bs[kk][tx << 2];
      acc[0][0] = fmaf(a.x, b.x, acc[0][0]);
      acc[0][1] = fmaf(a.x, b.y, acc[0][1]);
      acc[0][2] = fmaf(a.x, b.z, acc[0][2]);
      acc[0][3] = fmaf(a.x, b.w, acc[0][3]);
      acc[1][0] = fmaf(a.y, b.x, acc[1][0]);
      acc[1][1] = fmaf(a.y, b.y, acc[1][1]);
      acc[1][2] = fmaf(a.y, b.z, acc[1][2]);
      acc[1][3] = fmaf(a.y, b.w, acc[1][3]);
      acc[2][0] = fmaf(a.z, b.x, acc[2][0]);
      acc[2][1] = fmaf(a.z, b.y, acc[2][1]);
      acc[2][2] = fmaf(a.z, b.z, acc[2][2]);
      acc[2][3] = fmaf(a.z, b.w, acc[2][3]);
      acc[3][0] = fmaf(a.w, b.x, acc[3][0]);
      acc[3][1] = fmaf(a.w, b.y, acc[3][1]);
      acc[3][2] = fmaf(a.w, b.z, acc[3][2]);
      acc[3][3] = fmaf(a.w, b.w, acc[3][3]);
    }
    __syncthreads();
  }

#pragma unroll
  for (int i = 0; i < 4; i++) {
    int m = bm + (ty << 2) + i;
#pragma unroll
    for (int j = 0; j < 4; j++) {
      int n = bn + (tx << 2) + j;
      float val = acc[i][j] + bias[n];
      if (outF) outF[(size_t)m * orow + obase + (n / chunk) * gstride + (n % chunk)] = val;
      if (outB) outB[(size_t)m * N + n] = val;
    }
  }
}

// RoPE: cos has 16 entries -> rotates dims [96:112) of each 128-dim head
// (8+8 rotate-half); dims [112:128) pass through. In-place on q_full/k_full;
// emits the 32-dim roped k_rot to its d_out region (fp32).
__global__ __launch_bounds__(256) void rope_kernel(
    float* __restrict__ qf, float* __restrict__ kf, float* __restrict__ krot_out) {
  int idx = blockIdx.x * 256 + threadIdx.x;  // over M_*H_*8
  int j  = idx & 7;
  int h  = (idx >> 3) & (H_ - 1);
  int bs = idx >> 7;
  if (bs >= M_) return;
  int s = bs & (S_ - 1);
  float t = (float)s / 40.0f;
  float ang = t * exp2f(-1.6609640474436813f * (float)j);  // 10000^(-j/8)
  float c = cosf(ang), sn = sinf(ang);

  size_t base = (size_t)bs * 2048 + h * 128 + 96;
  float x0 = qf[base + j], x1 = qf[base + j + 8];
  qf[base + j]     = x0 * c - x1 * sn;
  qf[base + j + 8] = x1 * c + x0 * sn;

  float y0 = kf[base + j], y1 = kf[base + j + 8];
  float r0 = y0 * c - y1 * sn;
  float r1 = y1 * c + y0 * sn;
  kf[base + j]     = r0;
  kf[base + j + 8] = r1;

  size_t ko = (size_t)bs * (H_ * DR_) + h * DR_;
  krot_out[ko + j]      = r0;
  krot_out[ko + j + 8]  = r1;
  krot_out[ko + 16 + j] = kf[base + 16 + j];
  krot_out[ko + 24 + j] = kf[base + 24 + j];
}

// Causal attention, one block per (b, h, q): scores -> softmax -> P@V.
__global__ __launch_bounds__(256) void attn_kernel(
    const float* __restrict__ qf, const float* __restrict__ kf,
    const float* __restrict__ vf, float* __restrict__ out) {
  __shared__ float sc[S_];
  __shared__ float qv[DH_];
  __shared__ float red[256];
  int bid = blockIdx.x;
  int q = bid & (S_ - 1);
  int h = (bid >> 11) & (H_ - 1);
  int b = bid >> 15;
  int tid = threadIdx.x;

  size_t qoff = ((size_t)(b * S_ + q)) * 2048 + h * 128;
  if (tid < 128) qv[tid] = qf[qoff + tid];
  __syncthreads();

  int nk = q + 1;
  float lmax = -1e30f;
  for (int k = tid; k < nk; k += 256) {
    const float* krow = kf + ((size_t)(b * S_ + k)) * 2048 + h * 128;
    float dot = 0.f;
#pragma unroll
    for (int d = 0; d < 128; d += 4) {
      float4 kv = *(const float4*)(krow + d);
      dot = fmaf(qv[d], kv.x, dot);
      dot = fmaf(qv[d + 1], kv.y, dot);
      dot = fmaf(qv[d + 2], kv.z, dot);
      dot = fmaf(qv[d + 3], kv.w, dot);
    }
    dot *= 0.08838834764831845f;  // 1/sqrt(128)
    sc[k] = dot;
    lmax = fmaxf(lmax, dot);
  }
  red[tid] = lmax;
  __syncthreads();
  for (int st = 128; st > 0; st >>= 1) {
    if (tid < st) red[tid] = fmaxf(red[tid], red[tid + st]);
    __syncthreads();
  }
  float mx = red[0];
  __syncthreads();

  float lsum = 0.f;
  for (int k = tid; k < nk; k += 256) {
    float p = expf(sc[k] - mx);
    sc[k] = p;
    lsum += p;
  }
  red[tid] = lsum;
  __syncthreads();
  for (int st = 128; st > 0; st >>= 1) {
    if (tid < st) red[tid] += red[tid + st];
    __syncthreads();
  }
  float inv_l = 1.0f / red[0];
  __syncthreads();

  int d = tid & 127;
  int half = tid >> 7;
  float acc = 0.f;
  for (int k = half; k < nk; k += 2) {
    acc = fmaf(sc[k], vf[((size_t)(b * S_ + k)) * 2048 + h * 128 + d], acc);
  }
  red[tid] = acc;
  __syncthreads();
  if (tid < 128) {
    out[qoff + tid] = (red[tid] + red[tid + 128]) * inv_l;
  }
}

extern "C" void kernel_launch(void* const* d_in, const int* in_sizes, int n_in,
                              void* d_out, int out_size, void* d_ws, size_t ws_size,
                              hipStream_t stream) {
  const float* h     = (const float*)d_in[0];
  const float* W_dkv = (const float*)d_in[1];
  const float* b_dkv = (const float*)d_in[2];
  const float* W_dq  = (const float*)d_in[3];
  const float* b_dq  = (const float*)d_in[4];
  const float* W_uk  = (const float*)d_in[5];
  const float* b_uk  = (const float*)d_in[6];
  const float* W_uv  = (const float*)d_in[7];
  const float* b_uv  = (const float*)d_in[8];
  const float* W_uq  = (const float*)d_in[9];
  const float* b_uq  = (const float*)d_in[10];
  const float* W_qr  = (const float*)d_in[11];
  const float* b_qr  = (const float*)d_in[12];
  const float* W_kr  = (const float*)d_in[13];
  const float* b_kr  = (const float*)d_in[14];
  const float* W_out = (const float*)d_in[15];
  const float* b_out = (const float*)d_in[16];

  float* out      = (float*)d_out;                 // (B,S,E)
  float* out_ckv  = out + (size_t)M_ * E_;         // (B,S,C)    @ 8,388,608
  float* out_krot = out_ckv + (size_t)M_ * C_;     // (B,S,H,DR) @ 10,485,760

  float* ws     = (float*)d_ws;
  float* ws_ckv = ws;                 // 4096*512
  float* ws_cq  = ws + 2097152;       // 4096*512
  float* ws_q   = ws + 4194304;       // 4096*2048
  float* ws_k   = ws + 12582912;      // 4096*2048
  float* ws_v   = ws + 20971520;      // 4096*2048
  float* ws_ao  = ws + 29360128;      // 4096*2048

  dim3 blk(256);

  // c_kv = h @ W_dkv + b   (fp32 -> ws; copy -> d_out region 1)
  gemm_kernel<<<dim3(C_ / 64, M_ / 64), blk, 0, stream>>>(
      h, W_dkv, b_dkv, ws_ckv, C_, C_, C_, 0, out_ckv, M_, C_, E_);
  // c_q = h @ W_dq + b
  gemm_kernel<<<dim3(C_ / 64, M_ / 64), blk, 0, stream>>>(
      h, W_dq, b_dq, ws_cq, C_, C_, C_, 0, nullptr, M_, C_, E_);
  // k_rot_pre = h @ W_kr + b  -> k_full[..., 96:128]
  gemm_kernel<<<dim3((H_ * DR_) / 64, M_ / 64), blk, 0, stream>>>(
      h, W_kr, b_kr, ws_k, 2048, DR_, DH_, SP_, nullptr, M_, H_ * DR_, E_);
  // k_base = c_kv @ W_uk + b  -> k_full[..., 0:96]
  gemm_kernel<<<dim3((H_ * SP_) / 64, M_ / 64), blk, 0, stream>>>(
      ws_ckv, W_uk, b_uk, ws_k, 2048, SP_, DH_, 0, nullptr, M_, H_ * SP_, C_);
  // v = c_kv @ W_uv + b
  gemm_kernel<<<dim3((H_ * DH_) / 64, M_ / 64), blk, 0, stream>>>(
      ws_ckv, W_uv, b_uv, ws_v, 2048, 2048, 2048, 0, nullptr, M_, H_ * DH_, C_);
  // q_base = c_q @ W_uq + b  -> q_full[..., 0:96]
  gemm_kernel<<<dim3((H_ * SP_) / 64, M_ / 64), blk, 0, stream>>>(
      ws_cq, W_uq, b_uq, ws_q, 2048, SP_, DH_, 0, nullptr, M_, H_ * SP_, C_);
  // q_rot = c_q @ W_qr + b  -> q_full[..., 96:128]
  gemm_kernel<<<dim3((H_ * DR_) / 64, M_ / 64), blk, 0, stream>>>(
      ws_cq, W_qr, b_qr, ws_q, 2048, DR_, DH_, SP_, nullptr, M_, H_ * DR_, C_);
  // rope in-place on q_full/k_full; emits k_rot to d_out region 2
  rope_kernel<<<(M_ * H_ * 8) / 256, blk, 0, stream>>>(ws_q, ws_k, out_krot);
  // causal attention
  attn_kernel<<<B_ * H_ * S_, blk, 0, stream>>>(ws_q, ws_k, ws_v, ws_ao);
  // out = attn_out @ W_out + b  -> d_out region 0
  gemm_kernel<<<dim3(E_ / 64, M_ / 64), blk, 0, stream>>>(
      ws_ao, W_out, b_out, nullptr, E_, E_, E_, 0, out, M_, E_, E_);
}

// Round 5
// 1704.466 us; speedup vs baseline: 5.7347x; 5.7347x over previous
//
#include <hip/hip_runtime.h>
#include <hip/hip_bf16.h>

// MLA forward. Storage dtype fp32. GEMMs fp32 vector; attention = flash-style
// bf16 MFMA (Q/K/V cast at staging, fp32 softmax + O accum).
// Outputs (flat fp32): out[8,388,608] | c_kv[2,097,152] | k_rot[2,097,152].
#define B_   2
#define S_   2048
#define E_   2048
#define H_   16
#define DH_  128
#define DR_  32
#define SP_  96
#define C_   512
#define M_   (B_ * S_)   // 4096 rows

#define LOG2E 1.4426950408889634f

typedef __attribute__((ext_vector_type(8))) short short8;
typedef __attribute__((ext_vector_type(4))) float floatx4;

__device__ __forceinline__ unsigned short f2bf(float f) {
  unsigned u = __float_as_uint(f);
  unsigned r = (u + 0x7fff + ((u >> 16) & 1)) >> 16;  // RNE
  return (unsigned short)r;
}

// ---------------- fp32 GEMM (unchanged from passing round 4) ----------------
__global__ __launch_bounds__(256) void gemm_kernel(
    const float* __restrict__ A, const float* __restrict__ W,
    const float* __restrict__ bias,
    float* __restrict__ outF, int orow, int chunk, int gstride, int obase,
    float* __restrict__ outB,
    int M, int N, int K) {
  __shared__ float As[16][64];
  __shared__ float Bs[16][68];
  int tid = threadIdx.x;
  int tx = tid & 15, ty = tid >> 4;
  int bm = blockIdx.y * 64, bn = blockIdx.x * 64;
  float acc[4][4] = {};

  int am  = tid >> 2;
  int ak  = (tid & 3) << 2;
  int bk  = tid >> 4;
  int bn0 = (tid & 15) << 2;

  const float* Aptr = A + (size_t)(bm + am) * K + ak;
  const float* Wptr = W + (size_t)bk * N + bn + bn0;

  for (int k0 = 0; k0 < K; k0 += 16) {
    float4 av = *(const float4*)(Aptr + k0);
    float4 wv = *(const float4*)(Wptr + (size_t)k0 * N);
    As[ak + 0][am] = av.x;
    As[ak + 1][am] = av.y;
    As[ak + 2][am] = av.z;
    As[ak + 3][am] = av.w;
    *(float4*)&Bs[bk][bn0] = wv;
    __syncthreads();
#pragma unroll
    for (int kk = 0; kk < 16; kk++) {
      float4 a = *(const float4*)&As[kk][ty << 2];
      float4 b = *(const float4*)&Bs[kk][tx << 2];
      acc[0][0] = fmaf(a.x, b.x, acc[0][0]);
      acc[0][1] = fmaf(a.x, b.y, acc[0][1]);
      acc[0][2] = fmaf(a.x, b.z, acc[0][2]);
      acc[0][3] = fmaf(a.x, b.w, acc[0][3]);
      acc[1][0] = fmaf(a.y, b.x, acc[1][0]);
      acc[1][1] = fmaf(a.y, b.y, acc[1][1]);
      acc[1][2] = fmaf(a.y, b.z, acc[1][2]);
      acc[1][3] = fmaf(a.y, b.w, acc[1][3]);
      acc[2][0] = fmaf(a.z, b.x, acc[2][0]);
      acc[2][1] = fmaf(a.z, b.y, acc[2][1]);
      acc[2][2] = fmaf(a.z, b.z, acc[2][2]);
      acc[2][3] = fmaf(a.z, b.w, acc[2][3]);
      acc[3][0] = fmaf(a.w, b.x, acc[3][0]);
      acc[3][1] = fmaf(a.w, b.y, acc[3][1]);
      acc[3][2] = fmaf(a.w, b.z, acc[3][2]);
      acc[3][3] = fmaf(a.w, b.w, acc[3][3]);
    }
    __syncthreads();
  }

#pragma unroll
  for (int i = 0; i < 4; i++) {
    int m = bm + (ty << 2) + i;
#pragma unroll
    for (int j = 0; j < 4; j++) {
      int n = bn + (tx << 2) + j;
      float val = acc[i][j] + bias[n];
      if (outF) outF[(size_t)m * orow + obase + (n / chunk) * gstride + (n % chunk)] = val;
      if (outB) outB[(size_t)m * N + n] = val;
    }
  }
}

// ---------------- RoPE (unchanged) ----------------
__global__ __launch_bounds__(256) void rope_kernel(
    float* __restrict__ qf, float* __restrict__ kf, float* __restrict__ krot_out) {
  int idx = blockIdx.x * 256 + threadIdx.x;
  int j  = idx & 7;
  int h  = (idx >> 3) & (H_ - 1);
  int bs = idx >> 7;
  if (bs >= M_) return;
  int s = bs & (S_ - 1);
  float t = (float)s / 40.0f;
  float ang = t * exp2f(-1.6609640474436813f * (float)j);
  float c = cosf(ang), sn = sinf(ang);

  size_t base = (size_t)bs * 2048 + h * 128 + 96;
  float x0 = qf[base + j], x1 = qf[base + j + 8];
  qf[base + j]     = x0 * c - x1 * sn;
  qf[base + j + 8] = x1 * c + x0 * sn;

  float y0 = kf[base + j], y1 = kf[base + j + 8];
  float r0 = y0 * c - y1 * sn;
  float r1 = y1 * c + y0 * sn;
  kf[base + j]     = r0;
  kf[base + j + 8] = r1;

  size_t ko = (size_t)bs * (H_ * DR_) + h * DR_;
  krot_out[ko + j]      = r0;
  krot_out[ko + j + 8]  = r1;
  krot_out[ko + 16 + j] = kf[base + 16 + j];
  krot_out[ko + 24 + j] = kf[base + 24 + j];
}

// ---------------- flash attention, bf16 MFMA ----------------
// Block: 256 thr = 4 waves; each wave owns 16 q rows; block = 64-q tile of one
// (b,h). K-tiles of 32. MFMA 16x16x32 bf16 layouts (verified, learn_hip):
//   A-frag: A[m=lane&15][k=quad*8+j]   (j=0..7, one b128)
//   B-frag: B[k=quad*8+j][n=lane&15]
//   C/D   : D[row=quad*4+reg][col=lane&15]
#define KST 136   // K LDS row stride (bf16 units); 272B rows, 16B-aligned
#define VST 40    // Vt row stride; 80B rows
#define PST 40    // P row stride

__global__ __launch_bounds__(256) void attn_kernel(
    const float* __restrict__ qf, const float* __restrict__ kf,
    const float* __restrict__ vf, float* __restrict__ out) {
  __shared__ unsigned short Ks[32 * KST];    // K[k][d] bf16
  __shared__ unsigned short Vt[128 * VST];   // V^T: Vt[d][k] bf16
  __shared__ unsigned short Ps[4][16 * PST]; // per-wave P[q][k] bf16

  int bid = blockIdx.x;
  int qi  = bid & 31;
  int q0  = (31 - qi) << 6;    // large-q blocks launch first (tail balance)
  int bh  = bid >> 5;
  int h   = bh & 15;
  int b   = bh >> 4;

  int tid  = threadIdx.x;
  int wave = tid >> 6;
  int lane = tid & 63;
  int l16  = lane & 15;
  int quad = lane >> 4;

  // Q fragments: m = l16 (q row), k-dim = quad*8+j (+32 per chunk); scale folded.
  const float scale = 0.08838834764831845f;  // 1/sqrt(128)
  int qrow = q0 + wave * 16 + l16;
  const float* qbase = qf + ((size_t)(b * S_ + qrow)) * 2048 + h * 128 + quad * 8;
  short8 qfrag[4];
#pragma unroll
  for (int c = 0; c < 4; c++) {
    float4 u0 = *(const float4*)(qbase + c * 32);
    float4 u1 = *(const float4*)(qbase + c * 32 + 4);
    union { short8 v; unsigned short u[8]; } tmp;
    tmp.u[0] = f2bf(u0.x * scale); tmp.u[1] = f2bf(u0.y * scale);
    tmp.u[2] = f2bf(u0.z * scale); tmp.u[3] = f2bf(u0.w * scale);
    tmp.u[4] = f2bf(u1.x * scale); tmp.u[5] = f2bf(u1.y * scale);
    tmp.u[6] = f2bf(u1.z * scale); tmp.u[7] = f2bf(u1.w * scale);
    qfrag[c] = tmp.v;
  }

  floatx4 Oacc[8];
#pragma unroll
  for (int dt = 0; dt < 8; dt++) Oacc[dt] = (floatx4){0.f, 0.f, 0.f, 0.f};
  float m_run[4], l_run[4];
#pragma unroll
  for (int r = 0; r < 4; r++) { m_run[r] = -3.0e38f; l_run[r] = 0.f; }

  // staging index maps
  int srow = tid >> 3;         // K: row 0..31
  int sd0  = (tid & 7) * 16;   // K: d 0,16,..112
  int vrg  = tid & 7;          // V: row group (rows vrg*4..+3)
  int vdg  = tid >> 3;         // V: d group (d vdg*4..+3)

  int nkt = (q0 >> 5) + 2;
  for (int kt = 0; kt < nkt; kt++) {
    int kt0 = kt * 32;
    {  // stage K tile, row-major bf16
      const float* src = kf + ((size_t)(b * S_ + kt0 + srow)) * 2048 + h * 128 + sd0;
      unsigned short* dst = &Ks[srow * KST + sd0];
#pragma unroll
      for (int i = 0; i < 4; i++) {
        float4 v4 = *(const float4*)(src + i * 4);
        ushort4 w;
        w.x = f2bf(v4.x); w.y = f2bf(v4.y); w.z = f2bf(v4.z); w.w = f2bf(v4.w);
        *(ushort4*)(dst + i * 4) = w;
      }
    }
    {  // stage V tile transposed: Vt[d][k]
      const float* src0 = vf + ((size_t)(b * S_ + kt0 + vrg * 4)) * 2048 + h * 128 + vdg * 4;
#pragma unroll
      for (int rr = 0; rr < 4; rr++) {
        float4 v4 = *(const float4*)(src0 + (size_t)rr * 2048);
        Vt[(vdg * 4 + 0) * VST + vrg * 4 + rr] = f2bf(v4.x);
        Vt[(vdg * 4 + 1) * VST + vrg * 4 + rr] = f2bf(v4.y);
        Vt[(vdg * 4 + 2) * VST + vrg * 4 + rr] = f2bf(v4.z);
        Vt[(vdg * 4 + 3) * VST + vrg * 4 + rr] = f2bf(v4.w);
      }
    }
    __syncthreads();

    // S = Q K^T (two 16-wide n-tiles)
    floatx4 s[2];
#pragma unroll
    for (int nt = 0; nt < 2; nt++) {
      floatx4 acc = {0.f, 0.f, 0.f, 0.f};
#pragma unroll
      for (int c = 0; c < 4; c++) {
        short8 kfrag = *(const short8*)&Ks[(nt * 16 + l16) * KST + c * 32 + quad * 8];
        acc = __builtin_amdgcn_mfma_f32_16x16x32_bf16(qfrag[c], kfrag, acc, 0, 0, 0);
      }
      s[nt] = acc;
    }

    // causal mask + row max (rows live across the 16 lanes of a quad)
    int qg = q0 + wave * 16 + quad * 4;
    float rmax[4];
#pragma unroll
    for (int r = 0; r < 4; r++) {
      int q_r = qg + r;
      int k0g = kt0 + l16;
      if (k0g > q_r)      s[0][r] = -3.0e38f;
      if (k0g + 16 > q_r) s[1][r] = -3.0e38f;
      float mx = fmaxf(s[0][r], s[1][r]);
#pragma unroll
      for (int sh = 1; sh < 16; sh <<= 1) mx = fmaxf(mx, __shfl_xor(mx, sh));
      rmax[r] = mx;
    }
    float alpha[4];
#pragma unroll
    for (int r = 0; r < 4; r++) {
      float mnew = fmaxf(m_run[r], rmax[r]);
      alpha[r] = exp2f((m_run[r] - mnew) * LOG2E);
      m_run[r] = mnew;
    }

    // p = exp(s-m); write P (C-layout -> LDS), rowsum, l update
    unsigned short* P = Ps[wave];
    float psum;
#pragma unroll
    for (int r = 0; r < 4; r++) {
      float p0 = exp2f((s[0][r] - m_run[r]) * LOG2E);
      float p1 = exp2f((s[1][r] - m_run[r]) * LOG2E);
      P[(quad * 4 + r) * PST + l16]      = f2bf(p0);
      P[(quad * 4 + r) * PST + 16 + l16] = f2bf(p1);
      psum = p0 + p1;
#pragma unroll
      for (int sh = 1; sh < 16; sh <<= 1) psum += __shfl_xor(psum, sh);
      l_run[r] = l_run[r] * alpha[r] + psum;
    }

    // rescale O
#pragma unroll
    for (int dt = 0; dt < 8; dt++)
#pragma unroll
      for (int r = 0; r < 4; r++) Oacc[dt][r] *= alpha[r];

    // P as A-frag (LDS round trip), then O += P V
    short8 pfrag = *(const short8*)&P[l16 * PST + quad * 8];
#pragma unroll
    for (int dt = 0; dt < 8; dt++) {
      short8 vfrag = *(const short8*)&Vt[(dt * 16 + l16) * VST + quad * 8];
      Oacc[dt] = __builtin_amdgcn_mfma_f32_16x16x32_bf16(pfrag, vfrag, Oacc[dt], 0, 0, 0);
    }
    __syncthreads();
  }

  // epilogue: out[q][d] = O/l   (C-layout: row=quad*4+r, col=l16 within dt)
  int qg = q0 + wave * 16 + quad * 4;
#pragma unroll
  for (int r = 0; r < 4; r++) {
    float invl = 1.0f / l_run[r];
    float* dst = out + ((size_t)(b * S_ + qg + r)) * 2048 + h * 128 + l16;
#pragma unroll
    for (int dt = 0; dt < 8; dt++) dst[dt * 16] = Oacc[dt][r] * invl;
  }
}

extern "C" void kernel_launch(void* const* d_in, const int* in_sizes, int n_in,
                              void* d_out, int out_size, void* d_ws, size_t ws_size,
                              hipStream_t stream) {
  const float* h     = (const float*)d_in[0];
  const float* W_dkv = (const float*)d_in[1];
  const float* b_dkv = (const float*)d_in[2];
  const float* W_dq  = (const float*)d_in[3];
  const float* b_dq  = (const float*)d_in[4];
  const float* W_uk  = (const float*)d_in[5];
  const float* b_uk  = (const float*)d_in[6];
  const float* W_uv  = (const float*)d_in[7];
  const float* b_uv  = (const float*)d_in[8];
  const float* W_uq  = (const float*)d_in[9];
  const float* b_uq  = (const float*)d_in[10];
  const float* W_qr  = (const float*)d_in[11];
  const float* b_qr  = (const float*)d_in[12];
  const float* W_kr  = (const float*)d_in[13];
  const float* b_kr  = (const float*)d_in[14];
  const float* W_out = (const float*)d_in[15];
  const float* b_out = (const float*)d_in[16];

  float* out      = (float*)d_out;
  float* out_ckv  = out + (size_t)M_ * E_;
  float* out_krot = out_ckv + (size_t)M_ * C_;

  float* ws     = (float*)d_ws;
  float* ws_ckv = ws;
  float* ws_cq  = ws + 2097152;
  float* ws_q   = ws + 4194304;
  float* ws_k   = ws + 12582912;
  float* ws_v   = ws + 20971520;
  float* ws_ao  = ws + 29360128;

  dim3 blk(256);

  gemm_kernel<<<dim3(C_ / 64, M_ / 64), blk, 0, stream>>>(
      h, W_dkv, b_dkv, ws_ckv, C_, C_, C_, 0, out_ckv, M_, C_, E_);
  gemm_kernel<<<dim3(C_ / 64, M_ / 64), blk, 0, stream>>>(
      h, W_dq, b_dq, ws_cq, C_, C_, C_, 0, nullptr, M_, C_, E_);
  gemm_kernel<<<dim3((H_ * DR_) / 64, M_ / 64), blk, 0, stream>>>(
      h, W_kr, b_kr, ws_k, 2048, DR_, DH_, SP_, nullptr, M_, H_ * DR_, E_);
  gemm_kernel<<<dim3((H_ * SP_) / 64, M_ / 64), blk, 0, stream>>>(
      ws_ckv, W_uk, b_uk, ws_k, 2048, SP_, DH_, 0, nullptr, M_, H_ * SP_, C_);
  gemm_kernel<<<dim3((H_ * DH_) / 64, M_ / 64), blk, 0, stream>>>(
      ws_ckv, W_uv, b_uv, ws_v, 2048, 2048, 2048, 0, nullptr, M_, H_ * DH_, C_);
  gemm_kernel<<<dim3((H_ * SP_) / 64, M_ / 64), blk, 0, stream>>>(
      ws_cq, W_uq, b_uq, ws_q, 2048, SP_, DH_, 0, nullptr, M_, H_ * SP_, C_);
  gemm_kernel<<<dim3((H_ * DR_) / 64, M_ / 64), blk, 0, stream>>>(
      ws_cq, W_qr, b_qr, ws_q, 2048, DR_, DH_, SP_, nullptr, M_, H_ * DR_, C_);
  rope_kernel<<<(M_ * H_ * 8) / 256, blk, 0, stream>>>(ws_q, ws_k, out_krot);
  // flash MFMA attention: grid = B*H*(S/64) = 1024
  attn_kernel<<<B_ * H_ * (S_ / 64), blk, 0, stream>>>(ws_q, ws_k, ws_v, ws_ao);
  gemm_kernel<<<dim3(E_ / 64, M_ / 64), blk, 0, stream>>>(
      ws_ao, W_out, b_out, nullptr, E_, E_, E_, 0, out, M_, E_, E_);
}

// Round 7
// 749.592 us; speedup vs baseline: 13.0398x; 2.2739x over previous
//
#include <hip/hip_runtime.h>
#include <hip/hip_bf16.h>

// MLA forward. Storage fp32 in/out; whole internal pipeline bf16 MFMA with
// fp32 accumulation. GEMMs: 128x128 tile, BK=32, 16x16x32 bf16 MFMA.
// Outputs (flat fp32): out[8,388,608] | c_kv[2,097,152] | k_rot[2,097,152].
#define B_   2
#define S_   2048
#define E_   2048
#define H_   16
#define DH_  128
#define DR_  32
#define SP_  96
#define C_   512
#define M_   (B_ * S_)   // 4096 rows

#define LOG2E 1.4426950408889634f

typedef __attribute__((ext_vector_type(8))) short short8;
typedef __attribute__((ext_vector_type(4))) float floatx4;

__device__ __forceinline__ float bfu(unsigned short u) {
  return __uint_as_float((unsigned)u << 16);
}
__device__ __forceinline__ unsigned short f2bf(float f) {
  unsigned u = __float_as_uint(f);
  return (unsigned short)((u + 0x7fff + ((u >> 16) & 1)) >> 16);  // RNE
}

// ---------- fp32 -> bf16 bulk convert (for h) ----------
__global__ __launch_bounds__(256) void f2bf_kernel(
    const float* __restrict__ src, unsigned short* __restrict__ dst) {
  size_t i = ((size_t)blockIdx.x * 256 + threadIdx.x) * 4;
  float4 v = *(const float4*)(src + i);
  ushort4 w;
  w.x = f2bf(v.x); w.y = f2bf(v.y); w.z = f2bf(v.z); w.w = f2bf(v.w);
  *(ushort4*)(dst + i) = w;
}

// ---------- W[K][N] fp32 -> Wt[N][K] bf16 ----------
__global__ __launch_bounds__(256) void transpose_w_kernel(
    const float* __restrict__ W, unsigned short* __restrict__ Wt, int K, int N) {
  __shared__ unsigned short T[32][33];
  int n0 = blockIdx.x * 32, k0 = blockIdx.y * 32;
  int t = threadIdx.x, lane = t & 31, grp = t >> 5;
#pragma unroll
  for (int p = 0; p < 4; p++) {
    int k = p * 8 + grp;
    T[lane][k] = f2bf(W[(size_t)(k0 + k) * N + n0 + lane]);
  }
  __syncthreads();
#pragma unroll
  for (int p = 0; p < 4; p++) {
    int n = p * 8 + grp;
    Wt[(size_t)(n0 + n) * K + k0 + lane] = T[n][lane];
  }
}

// ---------- bf16 MFMA GEMM ----------
// C = A(MxK) @ Wt(NxK)^T + bias. A,Wt bf16 row-major; bias fp32.
// dst index = m*orow + obase + (n/chunk)*gstride + n%chunk (head remap).
// outF: fp32 remapped; outB: bf16 remapped (either may be null).
#define AST 40  // LDS row stride (bf16 units); 80B rows -> 2-way-max aliasing
__global__ __launch_bounds__(256) void mfma_gemm(
    const unsigned short* __restrict__ A, const unsigned short* __restrict__ Wt,
    const float* __restrict__ bias,
    float* __restrict__ outF, unsigned short* __restrict__ outB,
    int orow, int chunk, int gstride, int obase,
    int N, int K) {
  __shared__ unsigned short As[128 * AST];
  __shared__ unsigned short Bs[128 * AST];
  int tid = threadIdx.x;
  int lane = tid & 63, wave = tid >> 6;
  int l16 = lane & 15, quad = lane >> 4;
  int bm = blockIdx.y * 128, bn = blockIdx.x * 128;
  int wm = (wave & 1) * 64, wn = (wave >> 1) * 64;

  floatx4 acc[4][4];
#pragma unroll
  for (int mt = 0; mt < 4; mt++)
#pragma unroll
    for (int nt = 0; nt < 4; nt++) acc[mt][nt] = (floatx4){0.f, 0.f, 0.f, 0.f};

  int srow = tid >> 1;           // 0..127
  int shalf = (tid & 1) * 16;    // 0 / 16  -> each thread stages 16 elems/row

  const unsigned short* Ag = A + (size_t)(bm + srow) * K + shalf;
  const unsigned short* Bg = Wt + (size_t)(bn + srow) * K + shalf;
  unsigned short* Asw = &As[srow * AST + shalf];
  unsigned short* Bsw = &Bs[srow * AST + shalf];

  for (int k0 = 0; k0 < K; k0 += 32) {
    // full 128x32 tile per operand: 2 x short8 per thread (bugfix round 6)
    *(short8*)Asw       = *(const short8*)(Ag + k0);
    *(short8*)(Asw + 8) = *(const short8*)(Ag + k0 + 8);
    *(short8*)Bsw       = *(const short8*)(Bg + k0);
    *(short8*)(Bsw + 8) = *(const short8*)(Bg + k0 + 8);
    __syncthreads();
    short8 af[4], bfr[4];
#pragma unroll
    for (int mt = 0; mt < 4; mt++)
      af[mt] = *(const short8*)&As[(wm + mt * 16 + l16) * AST + quad * 8];
#pragma unroll
    for (int nt = 0; nt < 4; nt++)
      bfr[nt] = *(const short8*)&Bs[(wn + nt * 16 + l16) * AST + quad * 8];
#pragma unroll
    for (int mt = 0; mt < 4; mt++)
#pragma unroll
      for (int nt = 0; nt < 4; nt++)
        acc[mt][nt] = __builtin_amdgcn_mfma_f32_16x16x32_bf16(
            af[mt], bfr[nt], acc[mt][nt], 0, 0, 0);
    __syncthreads();
  }

  // C/D layout: D[row=quad*4+r][col=l16]
#pragma unroll
  for (int mt = 0; mt < 4; mt++) {
    int m0 = bm + wm + mt * 16 + quad * 4;
#pragma unroll
    for (int nt = 0; nt < 4; nt++) {
      int n = bn + wn + nt * 16 + l16;
      float bv = bias[n];
      int ncol = obase + (n / chunk) * gstride + (n % chunk);
#pragma unroll
      for (int r = 0; r < 4; r++) {
        float val = acc[mt][nt][r] + bv;
        size_t idx = (size_t)(m0 + r) * orow + ncol;
        if (outF) outF[idx] = val;
        if (outB) outB[idx] = f2bf(val);
      }
    }
  }
}

// ---------- RoPE on bf16 q/k; fp32 k_rot to d_out ----------
__global__ __launch_bounds__(256) void rope_kernel(
    unsigned short* __restrict__ qf, unsigned short* __restrict__ kf,
    float* __restrict__ krot_out) {
  int idx = blockIdx.x * 256 + threadIdx.x;
  int j  = idx & 7;
  int h  = (idx >> 3) & (H_ - 1);
  int bs = idx >> 7;
  if (bs >= M_) return;
  int s = bs & (S_ - 1);
  float t = (float)s / 40.0f;
  float ang = t * exp2f(-1.6609640474436813f * (float)j);  // 10000^(-j/8)
  float c = cosf(ang), sn = sinf(ang);

  size_t base = (size_t)bs * 2048 + h * 128 + 96;
  float x0 = bfu(qf[base + j]), x1 = bfu(qf[base + j + 8]);
  qf[base + j]     = f2bf(x0 * c - x1 * sn);
  qf[base + j + 8] = f2bf(x1 * c + x0 * sn);

  float y0 = bfu(kf[base + j]), y1 = bfu(kf[base + j + 8]);
  float r0 = y0 * c - y1 * sn;
  float r1 = y1 * c + y0 * sn;
  kf[base + j]     = f2bf(r0);
  kf[base + j + 8] = f2bf(r1);

  size_t ko = (size_t)bs * (H_ * DR_) + h * DR_;
  krot_out[ko + j]      = r0;
  krot_out[ko + j + 8]  = r1;
  krot_out[ko + 16 + j] = bfu(kf[base + 16 + j]);
  krot_out[ko + 24 + j] = bfu(kf[base + 24 + j]);
}

// ---------- flash attention, bf16 in / bf16 out ----------
#define KST 136
#define VST 40
#define PST 40
__global__ __launch_bounds__(256) void attn_kernel(
    const unsigned short* __restrict__ qf, const unsigned short* __restrict__ kf,
    const unsigned short* __restrict__ vf, unsigned short* __restrict__ ao) {
  __shared__ unsigned short Ks[32 * KST];
  __shared__ unsigned short Vt[128 * VST];
  __shared__ unsigned short Ps[4][16 * PST];

  int bid = blockIdx.x;
  int qi  = bid & 31;
  int q0  = (31 - qi) << 6;
  int bh  = bid >> 5;
  int h   = bh & 15;
  int b   = bh >> 4;

  int tid  = threadIdx.x;
  int wave = tid >> 6;
  int lane = tid & 63;
  int l16  = lane & 15;
  int quad = lane >> 4;

  const float scale = 0.08838834764831845f;  // 1/sqrt(128)
  int qrow = q0 + wave * 16 + l16;
  const unsigned short* qbase = qf + ((size_t)(b * S_ + qrow)) * 2048 + h * 128 + quad * 8;
  short8 qfrag[4];
#pragma unroll
  for (int c = 0; c < 4; c++) {
    union { short8 v; unsigned short u[8]; } in, outv;
    in.v = *(const short8*)(qbase + c * 32);
#pragma unroll
    for (int i = 0; i < 8; i++) outv.u[i] = f2bf(bfu(in.u[i]) * scale);
    qfrag[c] = outv.v;
  }

  floatx4 Oacc[8];
#pragma unroll
  for (int dt = 0; dt < 8; dt++) Oacc[dt] = (floatx4){0.f, 0.f, 0.f, 0.f};
  float m_run[4], l_run[4];
#pragma unroll
  for (int r = 0; r < 4; r++) { m_run[r] = -3.0e38f; l_run[r] = 0.f; }

  int srow = tid >> 3;         // K: row 0..31
  int sd0  = (tid & 7) * 16;   // K: d group
  int vrg  = tid & 7;          // V: k-group
  int vdg  = tid >> 3;         // V: d-group

  int nkt = (q0 >> 5) + 2;
  for (int kt = 0; kt < nkt; kt++) {
    int kt0 = kt * 32;
    {  // K tile: straight bf16 copy
      const unsigned short* src = kf + ((size_t)(b * S_ + kt0 + srow)) * 2048 + h * 128 + sd0;
      unsigned short* dst = &Ks[srow * KST + sd0];
      *(short8*)dst = *(const short8*)src;
      *(short8*)(dst + 8) = *(const short8*)(src + 8);
    }
    {  // V tile transposed
      const unsigned short* src0 = vf + ((size_t)(b * S_ + kt0 + vrg * 4)) * 2048 + h * 128 + vdg * 4;
#pragma unroll
      for (int rr = 0; rr < 4; rr++) {
        ushort4 v4 = *(const ushort4*)(src0 + (size_t)rr * 2048);
        Vt[(vdg * 4 + 0) * VST + vrg * 4 + rr] = v4.x;
        Vt[(vdg * 4 + 1) * VST + vrg * 4 + rr] = v4.y;
        Vt[(vdg * 4 + 2) * VST + vrg * 4 + rr] = v4.z;
        Vt[(vdg * 4 + 3) * VST + vrg * 4 + rr] = v4.w;
      }
    }
    __syncthreads();

    floatx4 s[2];
#pragma unroll
    for (int nt = 0; nt < 2; nt++) {
      floatx4 a2 = {0.f, 0.f, 0.f, 0.f};
#pragma unroll
      for (int c = 0; c < 4; c++) {
        short8 kfrag = *(const short8*)&Ks[(nt * 16 + l16) * KST + c * 32 + quad * 8];
        a2 = __builtin_amdgcn_mfma_f32_16x16x32_bf16(qfrag[c], kfrag, a2, 0, 0, 0);
      }
      s[nt] = a2;
    }

    int qg = q0 + wave * 16 + quad * 4;
    float rmax[4];
#pragma unroll
    for (int r = 0; r < 4; r++) {
      int q_r = qg + r;
      int k0g = kt0 + l16;
      if (k0g > q_r)      s[0][r] = -3.0e38f;
      if (k0g + 16 > q_r) s[1][r] = -3.0e38f;
      float mx = fmaxf(s[0][r], s[1][r]);
#pragma unroll
      for (int sh = 1; sh < 16; sh <<= 1) mx = fmaxf(mx, __shfl_xor(mx, sh));
      rmax[r] = mx;
    }
    float alpha[4];
#pragma unroll
    for (int r = 0; r < 4; r++) {
      float mnew = fmaxf(m_run[r], rmax[r]);
      alpha[r] = exp2f((m_run[r] - mnew) * LOG2E);
      m_run[r] = mnew;
    }

    unsigned short* P = Ps[wave];
#pragma unroll
    for (int r = 0; r < 4; r++) {
      float p0 = exp2f((s[0][r] - m_run[r]) * LOG2E);
      float p1 = exp2f((s[1][r] - m_run[r]) * LOG2E);
      P[(quad * 4 + r) * PST + l16]      = f2bf(p0);
      P[(quad * 4 + r) * PST + 16 + l16] = f2bf(p1);
      float psum = p0 + p1;
#pragma unroll
      for (int sh = 1; sh < 16; sh <<= 1) psum += __shfl_xor(psum, sh);
      l_run[r] = l_run[r] * alpha[r] + psum;
    }

#pragma unroll
    for (int dt = 0; dt < 8; dt++)
#pragma unroll
      for (int r = 0; r < 4; r++) Oacc[dt][r] *= alpha[r];

    short8 pfrag = *(const short8*)&P[l16 * PST + quad * 8];
#pragma unroll
    for (int dt = 0; dt < 8; dt++) {
      short8 vfrag = *(const short8*)&Vt[(dt * 16 + l16) * VST + quad * 8];
      Oacc[dt] = __builtin_amdgcn_mfma_f32_16x16x32_bf16(pfrag, vfrag, Oacc[dt], 0, 0, 0);
    }
    __syncthreads();
  }

  int qg = q0 + wave * 16 + quad * 4;
#pragma unroll
  for (int r = 0; r < 4; r++) {
    float invl = 1.0f / l_run[r];
    unsigned short* dst = ao + ((size_t)(b * S_ + qg + r)) * 2048 + h * 128 + l16;
#pragma unroll
    for (int dt = 0; dt < 8; dt++) dst[dt * 16] = f2bf(Oacc[dt][r] * invl);
  }
}

extern "C" void kernel_launch(void* const* d_in, const int* in_sizes, int n_in,
                              void* d_out, int out_size, void* d_ws, size_t ws_size,
                              hipStream_t stream) {
  const float* h     = (const float*)d_in[0];
  const float* W_dkv = (const float*)d_in[1];
  const float* b_dkv = (const float*)d_in[2];
  const float* W_dq  = (const float*)d_in[3];
  const float* b_dq  = (const float*)d_in[4];
  const float* W_uk  = (const float*)d_in[5];
  const float* b_uk  = (const float*)d_in[6];
  const float* W_uv  = (const float*)d_in[7];
  const float* b_uv  = (const float*)d_in[8];
  const float* W_uq  = (const float*)d_in[9];
  const float* b_uq  = (const float*)d_in[10];
  const float* W_qr  = (const float*)d_in[11];
  const float* b_qr  = (const float*)d_in[12];
  const float* W_kr  = (const float*)d_in[13];
  const float* b_kr  = (const float*)d_in[14];
  const float* W_out = (const float*)d_in[15];
  const float* b_out = (const float*)d_in[16];

  float* out      = (float*)d_out;
  float* out_ckv  = out + (size_t)M_ * E_;
  float* out_krot = out_ckv + (size_t)M_ * C_;

  unsigned short* w16 = (unsigned short*)d_ws;
  unsigned short* h_bf   = w16;                 //  8,388,608
  unsigned short* q_bf   = w16 + 8388608;       //  8,388,608
  unsigned short* k_bf   = w16 + 16777216;      //  8,388,608
  unsigned short* v_bf   = w16 + 25165824;      //  8,388,608
  unsigned short* ao_bf  = w16 + 33554432;      //  8,388,608
  unsigned short* ckv_bf = w16 + 41943040;      //  2,097,152
  unsigned short* cq_bf  = w16 + 44040192;      //  2,097,152
  unsigned short* Wt_dkv = w16 + 46137344;      //  1,048,576
  unsigned short* Wt_dq  = w16 + 47185920;      //  1,048,576
  unsigned short* Wt_kr  = w16 + 48234496;      //  1,048,576
  unsigned short* Wt_uk  = w16 + 49283072;      //    786,432
  unsigned short* Wt_uv  = w16 + 50069504;      //  1,048,576
  unsigned short* Wt_uq  = w16 + 51118080;      //    786,432
  unsigned short* Wt_qr  = w16 + 51904512;      //    262,144
  unsigned short* Wt_out = w16 + 52166656;      //  4,194,304

  dim3 blk(256);

  // conversions / transposes
  f2bf_kernel<<<8192, blk, 0, stream>>>(h, h_bf);
  transpose_w_kernel<<<dim3(C_ / 32, E_ / 32), blk, 0, stream>>>(W_dkv, Wt_dkv, E_, C_);
  transpose_w_kernel<<<dim3(C_ / 32, E_ / 32), blk, 0, stream>>>(W_dq, Wt_dq, E_, C_);
  transpose_w_kernel<<<dim3((H_ * DR_) / 32, E_ / 32), blk, 0, stream>>>(W_kr, Wt_kr, E_, H_ * DR_);
  transpose_w_kernel<<<dim3((H_ * SP_) / 32, C_ / 32), blk, 0, stream>>>(W_uk, Wt_uk, C_, H_ * SP_);
  transpose_w_kernel<<<dim3((H_ * DH_) / 32, C_ / 32), blk, 0, stream>>>(W_uv, Wt_uv, C_, H_ * DH_);
  transpose_w_kernel<<<dim3((H_ * SP_) / 32, C_ / 32), blk, 0, stream>>>(W_uq, Wt_uq, C_, H_ * SP_);
  transpose_w_kernel<<<dim3((H_ * DR_) / 32, C_ / 32), blk, 0, stream>>>(W_qr, Wt_qr, C_, H_ * DR_);
  transpose_w_kernel<<<dim3(E_ / 32, E_ / 32), blk, 0, stream>>>(W_out, Wt_out, E_, E_);

  // projections (all bf16 MFMA)
  mfma_gemm<<<dim3(C_ / 128, M_ / 128), blk, 0, stream>>>(
      h_bf, Wt_dkv, b_dkv, out_ckv, ckv_bf, C_, C_, C_, 0, C_, E_);
  mfma_gemm<<<dim3(C_ / 128, M_ / 128), blk, 0, stream>>>(
      h_bf, Wt_dq, b_dq, nullptr, cq_bf, C_, C_, C_, 0, C_, E_);
  mfma_gemm<<<dim3((H_ * DR_) / 128, M_ / 128), blk, 0, stream>>>(
      h_bf, Wt_kr, b_kr, nullptr, k_bf, 2048, DR_, DH_, SP_, H_ * DR_, E_);
  mfma_gemm<<<dim3((H_ * SP_) / 128, M_ / 128), blk, 0, stream>>>(
      ckv_bf, Wt_uk, b_uk, nullptr, k_bf, 2048, SP_, DH_, 0, H_ * SP_, C_);
  mfma_gemm<<<dim3((H_ * DH_) / 128, M_ / 128), blk, 0, stream>>>(
      ckv_bf, Wt_uv, b_uv, nullptr, v_bf, 2048, DH_, DH_, 0, H_ * DH_, C_);
  mfma_gemm<<<dim3((H_ * SP_) / 128, M_ / 128), blk, 0, stream>>>(
      cq_bf, Wt_uq, b_uq, nullptr, q_bf, 2048, SP_, DH_, 0, H_ * SP_, C_);
  mfma_gemm<<<dim3((H_ * DR_) / 128, M_ / 128), blk, 0, stream>>>(
      cq_bf, Wt_qr, b_qr, nullptr, q_bf, 2048, DR_, DH_, SP_, H_ * DR_, C_);

  rope_kernel<<<(M_ * H_ * 8) / 256, blk, 0, stream>>>(q_bf, k_bf, out_krot);
  attn_kernel<<<B_ * H_ * (S_ / 64), blk, 0, stream>>>(q_bf, k_bf, v_bf, ao_bf);

  // out = ao @ W_out + b  (fp32 -> d_out region 0)
  mfma_gemm<<<dim3(E_ / 128, M_ / 128), blk, 0, stream>>>(
      ao_bf, Wt_out, b_out, out, nullptr, E_, E_, E_, 0, E_, E_);
}

// Round 8
// 583.219 us; speedup vs baseline: 16.7596x; 1.2853x over previous
//
#include <hip/hip_runtime.h>
#include <hip/hip_bf16.h>

// MLA forward. Storage fp32 in/out; internal pipeline bf16 MFMA, fp32 accum.
// Attention: flash-style, no-running-max softmax (scores bounded; fminf(80)
// guard), paired q-tiles for causal load balance, pre-transposed V.
// Outputs (flat fp32): out[8,388,608] | c_kv[2,097,152] | k_rot[2,097,152].
#define B_   2
#define S_   2048
#define E_   2048
#define H_   16
#define DH_  128
#define DR_  32
#define SP_  96
#define C_   512
#define M_   (B_ * S_)   // 4096 rows

#define LOG2E 1.4426950408889634f

typedef __attribute__((ext_vector_type(8))) short short8;
typedef __attribute__((ext_vector_type(4))) float floatx4;

__device__ __forceinline__ float bfu(unsigned short u) {
  return __uint_as_float((unsigned)u << 16);
}
__device__ __forceinline__ unsigned short f2bf(float f) {
  unsigned u = __float_as_uint(f);
  return (unsigned short)((u + 0x7fff + ((u >> 16) & 1)) >> 16);  // RNE
}

// ---------- fp32 -> bf16 bulk convert (for h) ----------
__global__ __launch_bounds__(256) void f2bf_kernel(
    const float* __restrict__ src, unsigned short* __restrict__ dst) {
  size_t i = ((size_t)blockIdx.x * 256 + threadIdx.x) * 4;
  float4 v = *(const float4*)(src + i);
  ushort4 w;
  w.x = f2bf(v.x); w.y = f2bf(v.y); w.z = f2bf(v.z); w.w = f2bf(v.w);
  *(ushort4*)(dst + i) = w;
}

// ---------- W[K][N] fp32 -> Wt[N][K] bf16 ----------
__global__ __launch_bounds__(256) void transpose_w_kernel(
    const float* __restrict__ W, unsigned short* __restrict__ Wt, int K, int N) {
  __shared__ unsigned short T[32][33];
  int n0 = blockIdx.x * 32, k0 = blockIdx.y * 32;
  int t = threadIdx.x, lane = t & 31, grp = t >> 5;
#pragma unroll
  for (int p = 0; p < 4; p++) {
    int k = p * 8 + grp;
    T[lane][k] = f2bf(W[(size_t)(k0 + k) * N + n0 + lane]);
  }
  __syncthreads();
#pragma unroll
  for (int p = 0; p < 4; p++) {
    int n = p * 8 + grp;
    Wt[(size_t)(n0 + n) * K + k0 + lane] = T[n][lane];
  }
}

// ---------- bf16 MFMA GEMM ----------
// C = A(MxK) @ Wt(NxK)^T + bias. A,Wt bf16 row-major; bias fp32.
// dst index = m*orow + obase + (n/chunk)*gstride + n%chunk (head remap).
// outF: fp32 remapped; outB: bf16 remapped (either may be null).
// biasM (optional): bias indexed by m (row) instead of n -- used for the
// swapped-operand (transposed-output) V projection.
#define AST 40  // LDS row stride (bf16); 80B rows
__global__ __launch_bounds__(256) void mfma_gemm(
    const unsigned short* __restrict__ A, const unsigned short* __restrict__ Wt,
    const float* __restrict__ bias, const float* __restrict__ biasM,
    float* __restrict__ outF, unsigned short* __restrict__ outB,
    int orow, int chunk, int gstride, int obase,
    int N, int K) {
  __shared__ unsigned short As[128 * AST];
  __shared__ unsigned short Bs[128 * AST];
  int tid = threadIdx.x;
  int lane = tid & 63, wave = tid >> 6;
  int l16 = lane & 15, quad = lane >> 4;
  int bm = blockIdx.y * 128, bn = blockIdx.x * 128;
  int wm = (wave & 1) * 64, wn = (wave >> 1) * 64;

  floatx4 acc[4][4];
#pragma unroll
  for (int mt = 0; mt < 4; mt++)
#pragma unroll
    for (int nt = 0; nt < 4; nt++) acc[mt][nt] = (floatx4){0.f, 0.f, 0.f, 0.f};

  int srow = tid >> 1;           // 0..127
  int shalf = (tid & 1) * 16;    // 0 / 16

  const unsigned short* Ag = A + (size_t)(bm + srow) * K + shalf;
  const unsigned short* Bg = Wt + (size_t)(bn + srow) * K + shalf;
  unsigned short* Asw = &As[srow * AST + shalf];
  unsigned short* Bsw = &Bs[srow * AST + shalf];

  for (int k0 = 0; k0 < K; k0 += 32) {
    *(short8*)Asw       = *(const short8*)(Ag + k0);
    *(short8*)(Asw + 8) = *(const short8*)(Ag + k0 + 8);
    *(short8*)Bsw       = *(const short8*)(Bg + k0);
    *(short8*)(Bsw + 8) = *(const short8*)(Bg + k0 + 8);
    __syncthreads();
    short8 af[4], bfr[4];
#pragma unroll
    for (int mt = 0; mt < 4; mt++)
      af[mt] = *(const short8*)&As[(wm + mt * 16 + l16) * AST + quad * 8];
#pragma unroll
    for (int nt = 0; nt < 4; nt++)
      bfr[nt] = *(const short8*)&Bs[(wn + nt * 16 + l16) * AST + quad * 8];
#pragma unroll
    for (int mt = 0; mt < 4; mt++)
#pragma unroll
      for (int nt = 0; nt < 4; nt++)
        acc[mt][nt] = __builtin_amdgcn_mfma_f32_16x16x32_bf16(
            af[mt], bfr[nt], acc[mt][nt], 0, 0, 0);
    __syncthreads();
  }

  // C/D layout: D[row=quad*4+r][col=l16]
#pragma unroll
  for (int mt = 0; mt < 4; mt++) {
    int m0 = bm + wm + mt * 16 + quad * 4;
    float bm4[4];
    if (biasM) {
#pragma unroll
      for (int r = 0; r < 4; r++) bm4[r] = biasM[m0 + r];
    }
#pragma unroll
    for (int nt = 0; nt < 4; nt++) {
      int n = bn + wn + nt * 16 + l16;
      float bv = biasM ? 0.f : bias[n];
      int ncol = obase + (n / chunk) * gstride + (n % chunk);
#pragma unroll
      for (int r = 0; r < 4; r++) {
        float val = acc[mt][nt][r] + (biasM ? bm4[r] : bv);
        size_t idx = (size_t)(m0 + r) * orow + ncol;
        if (outF) outF[idx] = val;
        if (outB) outB[idx] = f2bf(val);
      }
    }
  }
}

// ---------- RoPE on bf16 q/k; fp32 k_rot to d_out ----------
__global__ __launch_bounds__(256) void rope_kernel(
    unsigned short* __restrict__ qf, unsigned short* __restrict__ kf,
    float* __restrict__ krot_out) {
  int idx = blockIdx.x * 256 + threadIdx.x;
  int j  = idx & 7;
  int h  = (idx >> 3) & (H_ - 1);
  int bs = idx >> 7;
  if (bs >= M_) return;
  int s = bs & (S_ - 1);
  float t = (float)s / 40.0f;
  float ang = t * exp2f(-1.6609640474436813f * (float)j);  // 10000^(-j/8)
  float c = cosf(ang), sn = sinf(ang);

  size_t base = (size_t)bs * 2048 + h * 128 + 96;
  float x0 = bfu(qf[base + j]), x1 = bfu(qf[base + j + 8]);
  qf[base + j]     = f2bf(x0 * c - x1 * sn);
  qf[base + j + 8] = f2bf(x1 * c + x0 * sn);

  float y0 = bfu(kf[base + j]), y1 = bfu(kf[base + j + 8]);
  float r0 = y0 * c - y1 * sn;
  float r1 = y1 * c + y0 * sn;
  kf[base + j]     = f2bf(r0);
  kf[base + j + 8] = f2bf(r1);

  size_t ko = (size_t)bs * (H_ * DR_) + h * DR_;
  krot_out[ko + j]      = r0;
  krot_out[ko + j + 8]  = r1;
  krot_out[ko + 16 + j] = bfu(kf[base + 16 + j]);
  krot_out[ko + 24 + j] = bfu(kf[base + 24 + j]);
}

// ---------- flash attention v2: paired q-tiles, no running max ----------
// vt layout: [h*128+d][b*2048+s]  (row-major, orow 4096)
#define KST 136
#define VST 40
#define PST 40
__global__ __launch_bounds__(256) void attn_kernel(
    const unsigned short* __restrict__ qf, const unsigned short* __restrict__ kf,
    const unsigned short* __restrict__ vt, unsigned short* __restrict__ ao) {
  __shared__ unsigned short Ks[32 * KST];
  __shared__ unsigned short Vs[128 * VST];
  __shared__ unsigned short Ps[4][16 * PST];

  int bid = blockIdx.x;
  int jp  = bid & 15;          // pair index: q-tiles jp and 31-jp
  int bh  = bid >> 4;
  int h   = bh & 15;
  int b   = bh >> 4;

  int tid  = threadIdx.x;
  int wave = tid >> 6;
  int lane = tid & 63;
  int l16  = lane & 15;
  int quad = lane >> 4;

  // staging maps
  int srow  = tid >> 3;          // K rows 0..31
  int sd0   = (tid & 7) * 16;    // K d-offset
  int vrow  = tid >> 1;          // Vt rows 0..127 (d)
  int vhalf = (tid & 1) * 16;    // Vt k-offset

  // fold 1/sqrt(128) * log2(e) into Q so p = exp2(s) directly
  const float qscale = 0.08838834764831845f * LOG2E;

  for (int half = 0; half < 2; half++) {
    int jj = half ? (31 - jp) : jp;
    int q0 = jj << 6;

    int qrow = q0 + wave * 16 + l16;
    const unsigned short* qbase =
        qf + ((size_t)(b * S_ + qrow)) * 2048 + h * 128 + quad * 8;
    short8 qfrag[4];
#pragma unroll
    for (int c = 0; c < 4; c++) {
      union { short8 v; unsigned short u[8]; } in, outv;
      in.v = *(const short8*)(qbase + c * 32);
#pragma unroll
      for (int i = 0; i < 8; i++) outv.u[i] = f2bf(bfu(in.u[i]) * qscale);
      qfrag[c] = outv.v;
    }

    floatx4 Oacc[8];
#pragma unroll
    for (int dt = 0; dt < 8; dt++) Oacc[dt] = (floatx4){0.f, 0.f, 0.f, 0.f};
    float lpart[4] = {0.f, 0.f, 0.f, 0.f};

    int qg_lo = q0 + wave * 16;    // min q row of this wave
    int qg_hi = qg_lo + 15;
    int nkt = (q0 >> 5) + 2;

    for (int kt = 0; kt < nkt; kt++) {
      int kt0 = kt << 5;
      {  // stage K tile [32 k][128 d]
        const unsigned short* src =
            kf + ((size_t)(b * S_ + kt0 + srow)) * 2048 + h * 128 + sd0;
        unsigned short* dst = &Ks[srow * KST + sd0];
        *(short8*)dst       = *(const short8*)src;
        *(short8*)(dst + 8) = *(const short8*)(src + 8);
      }
      {  // stage V^T tile [128 d][32 k] -- straight copies from vt
        const unsigned short* src =
            vt + ((size_t)(h * 128 + vrow)) * 4096 + b * 2048 + kt0 + vhalf;
        unsigned short* dst = &Vs[vrow * VST + vhalf];
        *(short8*)dst       = *(const short8*)src;
        *(short8*)(dst + 8) = *(const short8*)(src + 8);
      }
      __syncthreads();

      if (kt0 <= qg_hi) {  // wave has at least one unmasked score
        bool diag = (kt0 + 31 > qg_lo);

        floatx4 s[2];
#pragma unroll
        for (int nt = 0; nt < 2; nt++) {
          floatx4 a2 = {0.f, 0.f, 0.f, 0.f};
#pragma unroll
          for (int c = 0; c < 4; c++) {
            short8 kfrag = *(const short8*)&Ks[(nt * 16 + l16) * KST + c * 32 + quad * 8];
            a2 = __builtin_amdgcn_mfma_f32_16x16x32_bf16(qfrag[c], kfrag, a2, 0, 0, 0);
          }
          s[nt] = a2;
        }

        unsigned short* P = Ps[wave];
#pragma unroll
        for (int r = 0; r < 4; r++) {
          float p0 = exp2f(fminf(s[0][r], 80.f));
          float p1 = exp2f(fminf(s[1][r], 80.f));
          if (diag) {
            int q_r = qg_lo + quad * 4 + r;
            if (kt0 + l16 > q_r)      p0 = 0.f;
            if (kt0 + 16 + l16 > q_r) p1 = 0.f;
          }
          P[(quad * 4 + r) * PST + l16]      = f2bf(p0);
          P[(quad * 4 + r) * PST + 16 + l16] = f2bf(p1);
          lpart[r] += p0 + p1;
        }

        short8 pfrag = *(const short8*)&P[l16 * PST + quad * 8];
#pragma unroll
        for (int dt = 0; dt < 8; dt++) {
          short8 vfrag = *(const short8*)&Vs[(dt * 16 + l16) * VST + quad * 8];
          Oacc[dt] = __builtin_amdgcn_mfma_f32_16x16x32_bf16(pfrag, vfrag, Oacc[dt], 0, 0, 0);
        }
      }
      __syncthreads();
    }

    // epilogue: one l-reduction per q-tile
    float linv[4];
#pragma unroll
    for (int r = 0; r < 4; r++) {
      float ls = lpart[r];
#pragma unroll
      for (int sh = 1; sh < 16; sh <<= 1) ls += __shfl_xor(ls, sh);
      linv[r] = 1.0f / ls;
    }
    int qg = q0 + wave * 16 + quad * 4;
#pragma unroll
    for (int r = 0; r < 4; r++) {
      unsigned short* dst = ao + ((size_t)(b * S_ + qg + r)) * 2048 + h * 128 + l16;
#pragma unroll
      for (int dt = 0; dt < 8; dt++) dst[dt * 16] = f2bf(Oacc[dt][r] * linv[r]);
    }
  }
}

extern "C" void kernel_launch(void* const* d_in, const int* in_sizes, int n_in,
                              void* d_out, int out_size, void* d_ws, size_t ws_size,
                              hipStream_t stream) {
  const float* h     = (const float*)d_in[0];
  const float* W_dkv = (const float*)d_in[1];
  const float* b_dkv = (const float*)d_in[2];
  const float* W_dq  = (const float*)d_in[3];
  const float* b_dq  = (const float*)d_in[4];
  const float* W_uk  = (const float*)d_in[5];
  const float* b_uk  = (const float*)d_in[6];
  const float* W_uv  = (const float*)d_in[7];
  const float* b_uv  = (const float*)d_in[8];
  const float* W_uq  = (const float*)d_in[9];
  const float* b_uq  = (const float*)d_in[10];
  const float* W_qr  = (const float*)d_in[11];
  const float* b_qr  = (const float*)d_in[12];
  const float* W_kr  = (const float*)d_in[13];
  const float* b_kr  = (const float*)d_in[14];
  const float* W_out = (const float*)d_in[15];
  const float* b_out = (const float*)d_in[16];

  float* out      = (float*)d_out;
  float* out_ckv  = out + (size_t)M_ * E_;
  float* out_krot = out_ckv + (size_t)M_ * C_;

  unsigned short* w16 = (unsigned short*)d_ws;
  unsigned short* h_bf   = w16;                 //  8,388,608
  unsigned short* q_bf   = w16 + 8388608;       //  8,388,608
  unsigned short* k_bf   = w16 + 16777216;      //  8,388,608
  unsigned short* vt_bf  = w16 + 25165824;      //  8,388,608  (V^T)
  unsigned short* ao_bf  = w16 + 33554432;      //  8,388,608
  unsigned short* ckv_bf = w16 + 41943040;      //  2,097,152
  unsigned short* cq_bf  = w16 + 44040192;      //  2,097,152
  unsigned short* Wt_dkv = w16 + 46137344;      //  1,048,576
  unsigned short* Wt_dq  = w16 + 47185920;      //  1,048,576
  unsigned short* Wt_kr  = w16 + 48234496;      //  1,048,576
  unsigned short* Wt_uk  = w16 + 49283072;      //    786,432
  unsigned short* Wt_uv  = w16 + 50069504;      //  1,048,576
  unsigned short* Wt_uq  = w16 + 51118080;      //    786,432
  unsigned short* Wt_qr  = w16 + 51904512;      //    262,144
  unsigned short* Wt_out = w16 + 52166656;      //  4,194,304

  dim3 blk(256);

  // conversions / transposes
  f2bf_kernel<<<8192, blk, 0, stream>>>(h, h_bf);
  transpose_w_kernel<<<dim3(C_ / 32, E_ / 32), blk, 0, stream>>>(W_dkv, Wt_dkv, E_, C_);
  transpose_w_kernel<<<dim3(C_ / 32, E_ / 32), blk, 0, stream>>>(W_dq, Wt_dq, E_, C_);
  transpose_w_kernel<<<dim3((H_ * DR_) / 32, E_ / 32), blk, 0, stream>>>(W_kr, Wt_kr, E_, H_ * DR_);
  transpose_w_kernel<<<dim3((H_ * SP_) / 32, C_ / 32), blk, 0, stream>>>(W_uk, Wt_uk, C_, H_ * SP_);
  transpose_w_kernel<<<dim3((H_ * DH_) / 32, C_ / 32), blk, 0, stream>>>(W_uv, Wt_uv, C_, H_ * DH_);
  transpose_w_kernel<<<dim3((H_ * SP_) / 32, C_ / 32), blk, 0, stream>>>(W_uq, Wt_uq, C_, H_ * SP_);
  transpose_w_kernel<<<dim3((H_ * DR_) / 32, C_ / 32), blk, 0, stream>>>(W_qr, Wt_qr, C_, H_ * DR_);
  transpose_w_kernel<<<dim3(E_ / 32, E_ / 32), blk, 0, stream>>>(W_out, Wt_out, E_, E_);

  // projections (all bf16 MFMA)
  mfma_gemm<<<dim3(C_ / 128, M_ / 128), blk, 0, stream>>>(
      h_bf, Wt_dkv, b_dkv, nullptr, out_ckv, ckv_bf, C_, C_, C_, 0, C_, E_);
  mfma_gemm<<<dim3(C_ / 128, M_ / 128), blk, 0, stream>>>(
      h_bf, Wt_dq, b_dq, nullptr, nullptr, cq_bf, C_, C_, C_, 0, C_, E_);
  mfma_gemm<<<dim3((H_ * DR_) / 128, M_ / 128), blk, 0, stream>>>(
      h_bf, Wt_kr, b_kr, nullptr, nullptr, k_bf, 2048, DR_, DH_, SP_, H_ * DR_, E_);
  mfma_gemm<<<dim3((H_ * SP_) / 128, M_ / 128), blk, 0, stream>>>(
      ckv_bf, Wt_uk, b_uk, nullptr, nullptr, k_bf, 2048, SP_, DH_, 0, H_ * SP_, C_);
  // V^T = W_uv^T @ c_kv^T : swapped operands -> output rows = h*128+d,
  // cols = b*2048+s. biasM = b_uv (row axis).
  mfma_gemm<<<dim3(M_ / 128, (H_ * DH_) / 128), blk, 0, stream>>>(
      Wt_uv, ckv_bf, nullptr, b_uv, nullptr, vt_bf, M_, M_, M_, 0, M_, C_);
  mfma_gemm<<<dim3((H_ * SP_) / 128, M_ / 128), blk, 0, stream>>>(
      cq_bf, Wt_uq, b_uq, nullptr, nullptr, q_bf, 2048, SP_, DH_, 0, H_ * SP_, C_);
  mfma_gemm<<<dim3((H_ * DR_) / 128, M_ / 128), blk, 0, stream>>>(
      cq_bf, Wt_qr, b_qr, nullptr, nullptr, q_bf, 2048, DR_, DH_, SP_, H_ * DR_, C_);

  rope_kernel<<<(M_ * H_ * 8) / 256, blk, 0, stream>>>(q_bf, k_bf, out_krot);
  // paired-q flash attention: grid = B*H*16 = 512
  attn_kernel<<<B_ * H_ * 16, blk, 0, stream>>>(q_bf, k_bf, vt_bf, ao_bf);

  // out = ao @ W_out + b  (fp32 -> d_out region 0)
  mfma_gemm<<<dim3(E_ / 128, M_ / 128), blk, 0, stream>>>(
      ao_bf, Wt_out, b_out, nullptr, out, nullptr, E_, E_, E_, 0, E_, E_);
}